// Round 1
// baseline (277.979 us; speedup 1.0000x reference)
//
#include <hip/hip_runtime.h>
#include <stdint.h>

#define NB 8
#define NC 256
#define NE 128
#define NHW 4096

typedef __bf16 v8bf __attribute__((ext_vector_type(8)));
typedef float v4f __attribute__((ext_vector_type(4)));

#if __has_builtin(__builtin_amdgcn_exp2f)
#define EXP2F(x) __builtin_amdgcn_exp2f(x)
#else
#define EXP2F(x) exp2f(x)
#endif

// fp32 -> bf16 round-to-nearest-even (bit trick; finite inputs only)
__device__ __forceinline__ unsigned short f2bf(float x) {
    union { float f; unsigned int u; } v; v.f = x;
    unsigned int r = v.u + 0x7fffu + ((v.u >> 16) & 1u);
    return (unsigned short)(r >> 16);
}

// ---------------- K0: cast weights to bf16. Wbf[e][c], e<128 = w_theta * (scale*log2e), e>=128 = w_phi
__global__ __launch_bounds__(256) void cast_w_kernel(const float* __restrict__ wt,
                                                     const float* __restrict__ wp,
                                                     unsigned short* __restrict__ Wbf) {
    int i = blockIdx.x * 256 + threadIdx.x;                 // 0..65535
    const float QS = 0.08838834764831845f * 1.4426950408889634f; // 1/sqrt(128) * log2(e)
    float v = (i < 32768) ? wt[i] * QS : wp[i - 32768];
    Wbf[i] = f2bf(v);
}

// ---------------- K1: cast l -> bf16 (this IS V^T in PV B-operand layout: rows c, contiguous k)
__global__ __launch_bounds__(256) void cast_v_kernel(const float* __restrict__ l,
                                                     unsigned short* __restrict__ Vbf) {
    int i = blockIdx.x * 256 + threadIdx.x;                 // float4 index, 2,097,152 total
    float4 v = ((const float4*)l)[i];
    ushort4 o;
    o.x = f2bf(v.x); o.y = f2bf(v.y); o.z = f2bf(v.z); o.w = f2bf(v.w);
    ((ushort4*)Vbf)[i] = o;
}

// ---------------- K2: projection. Per block: batch b, 64-q tile.
// Q[b][q][e] = sum_c l[b][c][q] * Wtheta[e][c] (pre-scaled), K likewise with Wphi.
// GEMM M=64(q) N=256(128 theta | 128 phi) K=256(c); A staged via LDS transpose.
__global__ __launch_bounds__(256, 2) void proj_kernel(const float* __restrict__ l,
                                                      const unsigned short* __restrict__ Wbf,
                                                      unsigned short* __restrict__ Qbf,
                                                      unsigned short* __restrict__ Kbf) {
    __shared__ __align__(16) unsigned short A[64][264];     // [q][c], +8 pad, 33792 B
    const int tid = threadIdx.x;
    const int b = blockIdx.x & 7;
    const int qt = (blockIdx.x >> 3) << 6;
    const float* lb = l + (b * NC * NHW + qt);

    // stage l[b][c][qt:qt+64] -> A[q][c] bf16 (transpose on LDS write)
    for (int s = 0; s < 16; ++s) {
        int f = tid + s * 256;                              // 4096 float4 chunks
        int c = f >> 4, j = f & 15;
        float4 v = *(const float4*)(lb + c * NHW + j * 4);
        A[j * 4 + 0][c] = f2bf(v.x);
        A[j * 4 + 1][c] = f2bf(v.y);
        A[j * 4 + 2][c] = f2bf(v.z);
        A[j * 4 + 3][c] = f2bf(v.w);
    }
    __syncthreads();

    const int w = tid >> 6, L = tid & 63;
    const int l15 = L & 15, q4 = L >> 4;
    const v4f vz = {0.f, 0.f, 0.f, 0.f};
    v4f acc[4][4];
    for (int mt = 0; mt < 4; ++mt)
        for (int nt = 0; nt < 4; ++nt) acc[mt][nt] = vz;

    // wave w owns n in [64w, 64w+64)
    for (int kf = 0; kf < 8; ++kf) {
        int kc = kf * 32 + q4 * 8;
        v8bf a[4], bb[4];
        for (int mt = 0; mt < 4; ++mt)
            a[mt] = *(const v8bf*)&A[mt * 16 + l15][kc];
        for (int nt = 0; nt < 4; ++nt)
            bb[nt] = *(const v8bf*)(Wbf + (w * 64 + nt * 16 + l15) * 256 + kc);
        for (int mt = 0; mt < 4; ++mt)
            for (int nt = 0; nt < 4; ++nt)
                acc[mt][nt] = __builtin_amdgcn_mfma_f32_16x16x32_bf16(a[mt], bb[nt], acc[mt][nt], 0, 0, 0);
    }

    // C/D layout: col(n)=lane&15, row(m)=(lane>>4)*4+reg  [m89-verified]
    unsigned short* dst = (w < 2) ? Qbf : Kbf;
    const int ebase = (w & 1) * 64;
    for (int mt = 0; mt < 4; ++mt)
        for (int nt = 0; nt < 4; ++nt)
            for (int r = 0; r < 4; ++r) {
                int q = qt + mt * 16 + q4 * 4 + r;
                int e = ebase + nt * 16 + l15;
                dst[(b * NHW + q) * NE + e] = f2bf(acc[mt][nt][r]);
            }
}

// ---------------- K3: flash attention (no-max softmax, deferred row-sum).
// Block: 256 thr = 4 waves; q-tile 64 (wave w owns q rows [16w,16w+16)); k-tile 64.
__global__ __launch_bounds__(256, 2) void attn_kernel(const unsigned short* __restrict__ Qbf,
                                                      const unsigned short* __restrict__ Kbf,
                                                      const unsigned short* __restrict__ Vbf,
                                                      float* __restrict__ out) {
    __shared__ __align__(16) unsigned char smem[65536];
    unsigned short* Ku = (unsigned short*)smem;             // [64][136]  17408 B
    unsigned short* Vu = (unsigned short*)(smem + 17408);   // [256][72]  36864 B
    unsigned short* Pu = (unsigned short*)(smem + 54272);   // [64][72]    9216 B

    const int tid = threadIdx.x;
    const int b = blockIdx.x & 7;                           // batch -> XCD round-robin for L2 locality
    const int qt = (blockIdx.x >> 3) << 6;
    const int w = tid >> 6;
    const int L = tid & 63;
    const int l15 = L & 15, q4 = L >> 4;

    const unsigned short* Qb = Qbf + ((b * NHW + qt) * NE);
    const unsigned short* Kb = Kbf + (b * NHW * NE);
    const unsigned short* Vb = Vbf + (b * NC * NHW);

    // Q fragments (held in regs whole kernel): A[m=lane&15][k=(lane>>4)*8+j]
    v8bf aq[4];
    {
        const unsigned short* qrow = Qb + (w * 16 + l15) * NE + q4 * 8;
        for (int kf = 0; kf < 4; ++kf)
            aq[kf] = *(const v8bf*)(qrow + kf * 32);
    }

    const v4f vz = {0.f, 0.f, 0.f, 0.f};
    v4f o4[16];
    for (int nt = 0; nt < 16; ++nt) o4[nt] = vz;
    float lacc[4] = {0.f, 0.f, 0.f, 0.f};

    for (int k0 = 0; k0 < NHW; k0 += 64) {
        // stage K tile [64 k][128 e]
        for (int s = 0; s < 4; ++s) {
            int f = tid + s * 256;
            int r = f >> 4, cc = f & 15;
            *(uint4*)&Ku[r * 136 + cc * 8] = *(const uint4*)(Kb + (k0 + r) * NE + cc * 8);
        }
        // stage V^T tile [256 c][64 k]
        for (int s = 0; s < 8; ++s) {
            int f = tid + s * 256;
            int c = f >> 3, cc = f & 7;
            *(uint4*)&Vu[c * 72 + cc * 8] = *(const uint4*)(Vb + c * NHW + k0 + cc * 8);
        }
        __syncthreads();

        // S = Q K^T  (16 MFMAs/wave)
        v4f s4[4];
        for (int nt = 0; nt < 4; ++nt) s4[nt] = vz;
        for (int kf = 0; kf < 4; ++kf)
            for (int nt = 0; nt < 4; ++nt) {
                v8bf bk = *(const v8bf*)&Ku[(nt * 16 + l15) * 136 + kf * 32 + q4 * 8];
                s4[nt] = __builtin_amdgcn_mfma_f32_16x16x32_bf16(aq[kf], bk, s4[nt], 0, 0, 0);
            }

        // P = 2^S (scale*log2e folded into Q); accumulate row-sum partials per lane
        for (int nt = 0; nt < 4; ++nt)
            for (int r = 0; r < 4; ++r) {
                float p = EXP2F(s4[nt][r]);
                lacc[r] += p;
                Pu[(w * 16 + q4 * 4 + r) * 72 + nt * 16 + l15] = f2bf(p);
            }

        // O += P V^T  (32 MFMAs/wave); P rows are wave-private -> no barrier needed
        v8bf ap0, ap1;
        {
            const unsigned short* prow = Pu + (w * 16 + l15) * 72 + q4 * 8;
            ap0 = *(const v8bf*)(prow);
            ap1 = *(const v8bf*)(prow + 32);
        }
        for (int nt = 0; nt < 16; ++nt) {
            const unsigned short* vrow = Vu + (nt * 16 + l15) * 72 + q4 * 8;
            o4[nt] = __builtin_amdgcn_mfma_f32_16x16x32_bf16(ap0, *(const v8bf*)(vrow), o4[nt], 0, 0, 0);
            o4[nt] = __builtin_amdgcn_mfma_f32_16x16x32_bf16(ap1, *(const v8bf*)(vrow + 32), o4[nt], 0, 0, 0);
        }
        __syncthreads();
    }

    // finish row sums: reduce over the 16 lanes (same q4 group) holding cols of each row
    float ls[4];
    for (int r = 0; r < 4; ++r) {
        float v = lacc[r];
        v += __shfl_xor(v, 1);
        v += __shfl_xor(v, 2);
        v += __shfl_xor(v, 4);
        v += __shfl_xor(v, 8);
        ls[r] = 1.0f / v;
    }

    // transpose O through LDS: Ot[c][q] fp32 (overlays staging buffers; barrier above covers reuse)
    float* Ot = (float*)smem;
    for (int nt = 0; nt < 16; ++nt)
        for (int r = 0; r < 4; ++r)
            Ot[(nt * 16 + l15) * 64 + (w * 16 + q4 * 4 + r)] = o4[nt][r] * ls[r];
    __syncthreads();

    // coalesced store: out[b][c][qt + 0:64]
    float* ob = out + (b * NC * NHW + qt);
    for (int s = 0; s < 16; ++s) {
        int f = tid + s * 256;
        int c = f >> 4, j = f & 15;
        *(float4*)&ob[c * NHW + j * 4] = *(const float4*)&Ot[c * 64 + j * 4];
    }
}

extern "C" void kernel_launch(void* const* d_in, const int* in_sizes, int n_in,
                              void* d_out, int out_size, void* d_ws, size_t ws_size,
                              hipStream_t stream) {
    const float* l  = (const float*)d_in[0];
    const float* wt = (const float*)d_in[1];
    const float* wp = (const float*)d_in[2];
    float* out = (float*)d_out;

    char* ws = (char*)d_ws;
    unsigned short* Wbf = (unsigned short*)ws;                          // 131072 B
    unsigned short* Qbf = (unsigned short*)(ws + 131072);               // 8 MB
    unsigned short* Kbf = (unsigned short*)(ws + 131072 + 8388608);     // 8 MB
    unsigned short* Vbf = (unsigned short*)(ws + 131072 + 16777216);    // 16 MB  (total ~32.1 MB)

    hipLaunchKernelGGL(cast_w_kernel, dim3(256),  dim3(256), 0, stream, wt, wp, Wbf);
    hipLaunchKernelGGL(cast_v_kernel, dim3(8192), dim3(256), 0, stream, l, Vbf);
    hipLaunchKernelGGL(proj_kernel,   dim3(512),  dim3(256), 0, stream, l, Wbf, Qbf, Kbf);
    hipLaunchKernelGGL(attn_kernel,   dim3(512),  dim3(256), 0, stream, Qbf, Kbf, Vbf, out);
}